// Round 1
// baseline (316.440 us; speedup 1.0000x reference)
//
#include <hip/hip_runtime.h>
#include <stdint.h>

typedef float  f32x4  __attribute__((ext_vector_type(4)));
typedef short  bf16x8 __attribute__((ext_vector_type(8)));

static constexpr int Bb = 4, Ll = 2048, DM = 1024, DI = 2048;
static constexpr int M  = Bb * Ll;        // 8192 rows
static constexpr int K1 = DM;             // 1024
static constexpr int K2 = DI;             // 2048
static constexpr int NPROJ = 256;         // 4 j-blocks * 64 (49 used)
static constexpr int CHUNK = 128, NCH = Ll / CHUNK;  // 16 chunks

__device__ __forceinline__ unsigned short f2bf(float f) {
  unsigned u = __float_as_uint(f);
  return (unsigned short)((u + 0x7FFFu + ((u >> 16) & 1u)) >> 16);
}

__device__ __forceinline__ void async16(const void* g, void* l) {
  __builtin_amdgcn_global_load_lds((__attribute__((address_space(1))) void*)g,
                                   (__attribute__((address_space(3))) void*)l,
                                   16, 0, 0);
}

// ---------------- K0: convert x->bf16, transpose W_in->bf16, build WbigT, bias ----
__global__ __launch_bounds__(256) void k0_prep(
    const float* __restrict__ x, const float* __restrict__ W_in,
    const float* __restrict__ conv_w, const float* __restrict__ conv_b,
    const float* __restrict__ W_delta, const float* __restrict__ b_delta,
    const float* __restrict__ W_B, const float* __restrict__ W_C,
    const float* __restrict__ Dv,
    unsigned short* __restrict__ x_bf,   // [M][K1]
    unsigned short* __restrict__ Wt,     // [2*DI][K1]  (W_in^T)
    unsigned short* __restrict__ WbigT,  // [NPROJ][DI]
    float* __restrict__ bias64)          // [64]
{
  const int t = threadIdx.x;
  const int bid = blockIdx.x;
  __shared__ float lds[64 * 65];

  if (bid < 4096) {                         // ---- x -> bf16 (8 elems/thread)
    size_t i0 = ((size_t)bid * 256 + t) * 8;
    float4 a = *(const float4*)(x + i0);
    float4 b = *(const float4*)(x + i0 + 4);
    union { unsigned short u[8]; bf16x8 v; } r;
    r.u[0] = f2bf(a.x); r.u[1] = f2bf(a.y); r.u[2] = f2bf(a.z); r.u[3] = f2bf(a.w);
    r.u[4] = f2bf(b.x); r.u[5] = f2bf(b.y); r.u[6] = f2bf(b.z); r.u[7] = f2bf(b.w);
    *(bf16x8*)(x_bf + i0) = r.v;
  } else if (bid < 4096 + 1024) {           // ---- W_in [1024][4096] -> Wt [4096][1024] bf16
    int q = bid - 4096;
    int tx = q & 63, ty = q >> 6;           // 64 n-tiles x 16 k-tiles
    int n0 = tx * 64, k0 = ty * 64;
    for (int i = t; i < 4096; i += 256) {
      int r = i >> 6, c = i & 63;
      lds[r * 65 + c] = W_in[(size_t)(k0 + r) * 4096 + n0 + c];
    }
    __syncthreads();
    for (int i = t; i < 4096; i += 256) {
      int n = i >> 6, kk = i & 63;
      Wt[(size_t)(n0 + n) * 1024 + k0 + kk] = f2bf(lds[kk * 65 + n]);
    }
  } else if (bid < 4096 + 1024 + 2048) {    // ---- WbigT[j*64+n][c] = wsel(c,n)*conv_w[c][j]
    int q = bid - (4096 + 1024);
    int id = q * 256 + t;                   // 524288 items
    int row = id >> 11, c = id & 2047;
    int n = row & 63, jb = row >> 6;
    float v = 0.f;
    if (n < 16)      v = W_delta[c * 16 + n];
    else if (n < 32) v = W_B[c * 16 + (n - 16)];
    else if (n < 48) v = W_C[c * 16 + (n - 32)];
    else if (n == 48) v = Dv[c];
    v *= conv_w[c * 4 + jb];
    WbigT[(size_t)row * 2048 + c] = f2bf(v);
  } else {                                  // ---- bias64[n] = conv_b @ wsel(:,n) (+ b_delta)
    int n = bid - (4096 + 1024 + 2048);     // 0..63, one block each
    float s = 0.f;
    if (n < 49) {
      for (int c = t; c < 2048; c += 256) {
        float w;
        if (n < 16)      w = W_delta[c * 16 + n];
        else if (n < 32) w = W_B[c * 16 + (n - 16)];
        else if (n < 48) w = W_C[c * 16 + (n - 32)];
        else             w = Dv[c];
        s += conv_b[c] * w;
      }
    }
    #pragma unroll
    for (int m_ = 32; m_ >= 1; m_ >>= 1) s += __shfl_xor(s, m_);
    if ((t & 63) == 0) lds[t >> 6] = s;
    __syncthreads();
    if (t == 0) {
      float tot = lds[0] + lds[1] + lds[2] + lds[3];
      if (n < 16) tot += b_delta[n];
      if (n >= 49) tot = 0.f;
      bias64[n] = tot;
    }
  }
}

// ---------------- GEMM: C = A[M][K] * Bt[N][K]^T, bf16 MFMA 16x16x32 ----------
// GATED: B-tile = [gate rows n0..n0+63 | in rows 2048+n0..] ; epilogue silu(g)*v -> bf16
// else : B-tile = rows n0..n0+127 ; epilogue raw f32
template <int BM, bool GATED>
__global__ __launch_bounds__(256) void gemm_k(
    const unsigned short* __restrict__ A,
    const unsigned short* __restrict__ Bt,
    void* __restrict__ outp, int K, int out_ld)
{
  const int tid = threadIdx.x;
  const int lane = tid & 63, wid = tid >> 6;
  const int wm = wid >> 1, wn = wid & 1;          // 2x2 waves
  const int lane15 = lane & 15, kg = lane >> 4;   // k-group 0..3
  const int m0 = blockIdx.y * BM;
  const int n0 = blockIdx.x * (GATED ? 64 : 128);

  constexpr int ACH = BM * 4;                     // A chunks (16B each)
  constexpr int TOT = ACH + 512;                  // + B chunks (128 rows * 4)
  __shared__ short sm[2][TOT * 8];

  f32x4 acc[BM / 32][4];
  #pragma unroll
  for (int a_ = 0; a_ < BM / 32; ++a_)
    #pragma unroll
    for (int b_ = 0; b_ < 4; ++b_) acc[a_][b_] = f32x4{0.f, 0.f, 0.f, 0.f};

  const int NT = K >> 5;

  auto stage = [&](int buf, int step) {
    const int kt = step << 5;
    #pragma unroll
    for (int i = 0; i < TOT / 256; ++i) {
      int q = i * 256 + tid;
      char* dst = (char*)(&sm[buf][0]) + q * 16;
      const unsigned short* src;
      if (q < ACH) {
        int row = q >> 2;
        int kc = (q & 3) ^ (row & 3);             // pre-swizzled source (rule #21)
        src = A + (size_t)(m0 + row) * K + kt + kc * 8;
      } else {
        int q2 = q - ACH;
        int row = q2 >> 2;
        int kc = (q2 & 3) ^ (row & 3);
        int grow;
        if (GATED) grow = (row < 64) ? (n0 + row) : (2048 + n0 + (row - 64));
        else       grow = n0 + row;
        src = Bt + (size_t)grow * K + kt + kc * 8;
      }
      async16(src, dst);
    }
  };

  stage(0, 0);
  __syncthreads();

  int buf = 0;
  for (int step = 0; step < NT; ++step) {
    if (step + 1 < NT) stage(buf ^ 1, step + 1);
    const char* smA = (const char*)(&sm[buf][0]);
    const char* smB = smA + ACH * 16;
    bf16x8 af[BM / 32], bfr[4];
    #pragma unroll
    for (int mf = 0; mf < BM / 32; ++mf) {
      int row = wm * (BM / 2) + mf * 16 + lane15;
      int kc = kg ^ (row & 3);
      af[mf] = *(const bf16x8*)(smA + row * 64 + kc * 16);
    }
    #pragma unroll
    for (int f = 0; f < 4; ++f) {
      int row;
      if (GATED) row = (f >> 1) * 64 + wn * 32 + (f & 1) * 16 + lane15;
      else       row = wn * 64 + f * 16 + lane15;
      int kc = kg ^ (row & 3);
      bfr[f] = *(const bf16x8*)(smB + row * 64 + kc * 16);
    }
    #pragma unroll
    for (int mf = 0; mf < BM / 32; ++mf)
      #pragma unroll
      for (int f = 0; f < 4; ++f)
        acc[mf][f] = __builtin_amdgcn_mfma_f32_16x16x32_bf16(af[mf], bfr[f], acc[mf][f], 0, 0, 0);
    __syncthreads();
    buf ^= 1;
  }

  if (GATED) {
    unsigned short* out = (unsigned short*)outp;
    #pragma unroll
    for (int mf = 0; mf < BM / 32; ++mf)
      #pragma unroll
      for (int f = 0; f < 2; ++f) {
        int col = n0 + wn * 32 + f * 16 + lane15;
        #pragma unroll
        for (int e = 0; e < 4; ++e) {
          int row = m0 + wm * (BM / 2) + mf * 16 + (lane >> 4) * 4 + e;
          float g = acc[mf][f][e], v = acc[mf][f + 2][e];
          float s = g / (1.f + __expf(-g));       // silu
          out[(size_t)row * out_ld + col] = f2bf(s * v);
        }
      }
  } else {
    float* out = (float*)outp;
    #pragma unroll
    for (int mf = 0; mf < BM / 32; ++mf)
      #pragma unroll
      for (int f = 0; f < 4; ++f) {
        int col = n0 + wn * 64 + f * 16 + lane15;
        #pragma unroll
        for (int e = 0; e < 4; ++e) {
          int row = m0 + wm * (BM / 2) + mf * 16 + (lane >> 4) * 4 + e;
          out[(size_t)row * out_ld + col] = acc[mf][f][e];
        }
      }
  }
}

// ---------------- K3: combine 4 j-blocks of G + per-chunk scan aggregates ----
__global__ __launch_bounds__(256) void k3_combine_scanA(
    const float* __restrict__ G, const float* __restrict__ bias64,
    float* __restrict__ a_arr, float* __restrict__ bd_arr,
    float* __restrict__ cm_arr, float* __restrict__ xcd_arr,
    float* __restrict__ aProd, float* __restrict__ hEnd)
{
  const int t = threadIdx.x;
  const int b = blockIdx.x >> 4, ch = blockIdx.x & 15;
  const int l0 = ch * CHUNK;
  __shared__ float comb[CHUNK][64];
  const size_t mbase = (size_t)b * 2048;

  for (int i = t; i < CHUNK * 64; i += 256) {
    int l = i >> 6, n = i & 63;
    float s = bias64[n];
    #pragma unroll
    for (int j = 0; j < 4; ++j) {
      int gl = l0 + l - 3 + j;                 // causal: skip gl<0 (left zero-pad)
      if (gl >= 0) s += G[(mbase + gl) * 256 + (j << 6) + n];
    }
    comb[l][n] = s;
  }
  __syncthreads();

  for (int i = t; i < CHUNK * 16; i += 256) {
    int l = i >> 4, n = i & 15;
    float d  = comb[l][n];                     // delta
    float la = -0.5f * logf(1.0f + (float)(n + 1) * 0.0625f);
    float a  = __expf(d * la);                 // A_d
    float bd = d * comb[l][16 + n];            // delta * Bm
    size_t gi = ((mbase + l0 + l) << 4) + n;
    a_arr[gi] = a; bd_arr[gi] = bd; cm_arr[gi] = comb[l][32 + n];
    comb[l][n] = a; comb[l][16 + n] = bd;      // reuse LDS for phase A
  }
  if (t < CHUNK) xcd_arr[mbase + l0 + t] = comb[t][48];
  __syncthreads();

  if (t < 16) {                                // per-chunk (prod A, h with h_in=0)
    float h = 0.f, p = 1.f;
    for (int l = 0; l < CHUNK; ++l) {
      float a = comb[l][t], bd = comb[l][16 + t];
      p *= a; h = a * h + bd;
    }
    int idx = ((b * 16 + ch) << 4) + t;
    aProd[idx] = p; hEnd[idx] = h;
  }
}

// ---------------- K4: scan chunk aggregates (tiny) ---------------------------
__global__ __launch_bounds__(64) void k4_scan_agg(
    const float* __restrict__ aProd, const float* __restrict__ hEnd,
    float* __restrict__ hIn)
{
  int t = threadIdx.x;                          // 64 = 4 b * 16 n
  int b = t >> 4, n = t & 15;
  float h = 0.f;
  for (int p = 0; p < NCH; ++p) {
    int idx = ((b * NCH + p) << 4) + n;
    hIn[idx] = h;
    h = aProd[idx] * h + hEnd[idx];
  }
}

// ---------------- K5: re-apply scan, y = sum_n Cm*h + xcD --------------------
__global__ __launch_bounds__(64) void k5_scanC(
    const float* __restrict__ a_arr, const float* __restrict__ bd_arr,
    const float* __restrict__ cm_arr, const float* __restrict__ xcd_arr,
    const float* __restrict__ hIn, float* __restrict__ y)
{
  const int t = threadIdx.x;
  const int b = blockIdx.x >> 4, ch = blockIdx.x & 15;
  if (t >= 16) return;
  const int n = t;
  const size_t base = (size_t)b * 2048 + ch * CHUNK;
  float h = hIn[((b * NCH + ch) << 4) + n];
  for (int l = 0; l < CHUNK; ++l) {
    size_t gi = ((base + l) << 4) + n;
    h = a_arr[gi] * h + bd_arr[gi];
    float p = cm_arr[gi] * h;
    p += __shfl_xor(p, 1); p += __shfl_xor(p, 2);
    p += __shfl_xor(p, 4); p += __shfl_xor(p, 8);
    if (n == 0) y[base + l] = p + xcd_arr[base + l];
  }
}

// ---------------- K6: out[m][:] = y[m] * w_out -------------------------------
__global__ __launch_bounds__(256) void k6_bcast(
    const float* __restrict__ y, const float* __restrict__ w_out,
    float* __restrict__ out)
{
  int m = blockIdx.x, t = threadIdx.x;
  float yv = y[m];
  float4 w4 = *(const float4*)(w_out + t * 4);
  float4 o; o.x = yv * w4.x; o.y = yv * w4.y; o.z = yv * w4.z; o.w = yv * w4.w;
  *(float4*)(out + (size_t)m * 1024 + t * 4) = o;
}

extern "C" void kernel_launch(void* const* d_in, const int* in_sizes, int n_in,
                              void* d_out, int out_size, void* d_ws, size_t ws_size,
                              hipStream_t stream) {
  const float* x       = (const float*)d_in[0];
  const float* W_in    = (const float*)d_in[1];
  const float* conv_w  = (const float*)d_in[2];
  const float* conv_b  = (const float*)d_in[3];
  const float* W_delta = (const float*)d_in[4];
  const float* b_delta = (const float*)d_in[5];
  const float* W_B     = (const float*)d_in[6];
  const float* W_C     = (const float*)d_in[7];
  const float* Dv      = (const float*)d_in[8];
  const float* w_out   = (const float*)d_in[9];

  char* ws = (char*)d_ws;
  size_t off = 0;
  auto alloc = [&](size_t bytes) {
    size_t cur = off; off = (cur + bytes + 255) & ~(size_t)255; return ws + cur;
  };
  unsigned short* x_bf  = (unsigned short*)alloc((size_t)M * K1 * 2);      // 16.8MB
  unsigned short* Wt    = (unsigned short*)alloc((size_t)4096 * K1 * 2);   //  8.4MB
  unsigned short* WbigT = (unsigned short*)alloc((size_t)NPROJ * K2 * 2);  //  1.0MB
  float* bias64 = (float*)alloc(64 * 4);
  unsigned short* xg    = (unsigned short*)alloc((size_t)M * DI * 2);      // 33.6MB
  float* G      = (float*)alloc((size_t)M * NPROJ * 4);                    //  8.4MB
  float* a_arr  = (float*)alloc((size_t)M * 16 * 4);
  float* bd_arr = (float*)alloc((size_t)M * 16 * 4);
  float* cm_arr = (float*)alloc((size_t)M * 16 * 4);
  float* xcd    = (float*)alloc((size_t)M * 4);
  float* aProd  = (float*)alloc(4 * NCH * 16 * 4);
  float* hEnd   = (float*)alloc(4 * NCH * 16 * 4);
  float* hIn    = (float*)alloc(4 * NCH * 16 * 4);
  float* yv     = (float*)alloc((size_t)M * 4);

  k0_prep<<<7232, 256, 0, stream>>>(x, W_in, conv_w, conv_b, W_delta, b_delta,
                                    W_B, W_C, Dv, x_bf, Wt, WbigT, bias64);
  gemm_k<128, true ><<<dim3(32, 64), 256, 0, stream>>>(x_bf, Wt, xg, K1, DI);
  gemm_k<64,  false><<<dim3(2, 128), 256, 0, stream>>>(xg, WbigT, G, K2, NPROJ);
  k3_combine_scanA<<<64, 256, 0, stream>>>(G, bias64, a_arr, bd_arr, cm_arr, xcd,
                                           aProd, hEnd);
  k4_scan_agg<<<1, 64, 0, stream>>>(aProd, hEnd, hIn);
  k5_scanC<<<64, 64, 0, stream>>>(a_arr, bd_arr, cm_arr, xcd, hIn, yv);
  k6_bcast<<<M, 256, 0, stream>>>(yv, w_out, (float*)d_out);
}